// Round 4
// baseline (772.687 us; speedup 1.0000x reference)
//
#include <hip/hip_runtime.h>

#define N_NODES 100000
#define N_EDGES 1600000
#define N_GRAPHS 2048
#define NFEAT 78
#define DIM 32
#define NLAYERS 5
#define OUTD 128
#define BN_EPS 1e-5f
#define NB 12500       // buckets = N_NODES/8
#define NPB 8          // nodes per bucket
#define BCAP 256       // bucket capacity (mean 128; Poisson overflow ~1e-22)
#define PGRP 64        // buckets per partial-stats slot
#define NSLOTS ((NB + PGRP - 1) / PGRP)   // 196

// ---------- bucket fill: bdata[b] <- src | (dst&7)<<20 ----------
__global__ __launch_bounds__(256) void bfill_kernel(
    const int* __restrict__ ei, int* __restrict__ bcnt, int* __restrict__ bdata)
{
    int e = blockIdx.x * 256 + threadIdx.x;
    if (e >= N_EDGES) return;
    int src = ei[e];
    int dst = ei[N_EDGES + e];
    int b = dst >> 3;
    int pos = atomicAdd(&bcnt[b], 1);
    if (pos < BCAP)
        __builtin_nontemporal_store(src | ((dst & 7) << 20), &bdata[b * BCAP + pos]);
}

// ---------- GEMM1 (8 threads/row): y = affine(h) @ W1 ----------
template<int K, bool AFF>
__global__ __launch_bounds__(256) void gemm1f_kernel(
    const float* __restrict__ h, const float* __restrict__ W,
    const float* __restrict__ ss, float* __restrict__ y)
{
    __shared__ float Wl[K * DIM];
    __shared__ float scl[DIM], shl[DIM];
    for (int i = threadIdx.x; i < K * DIM; i += 256) Wl[i] = W[i];
    if (AFF && threadIdx.x < DIM) {
        scl[threadIdx.x] = ss[threadIdx.x];
        shl[threadIdx.x] = ss[DIM + threadIdx.x];
    }
    __syncthreads();

    int t = blockIdx.x * 256 + threadIdx.x;
    int row = t >> 3;
    int c0 = (t & 7) * 4;

    float4 acc = make_float4(0.f, 0.f, 0.f, 0.f);
    const float* hr = h + (long)row * K;
    for (int k = 0; k < K; ++k) {
        float xv = hr[k];
        if (AFF) xv = fmaf(xv, scl[k], shl[k]);
        acc.x += xv * Wl[k * DIM + c0 + 0];
        acc.y += xv * Wl[k * DIM + c0 + 1];
        acc.z += xv * Wl[k * DIM + c0 + 2];
        acc.w += xv * Wl[k * DIM + c0 + 3];
    }
    *(float4*)(y + (long)row * DIM + c0) = acc;
}

// ---- fused per-bucket: sort edges by node, gather-agg, MLP2, BN partials ----
// block = one 8-node bucket; 32 threads per node (1 column each)
__global__ __launch_bounds__(256) void bucket_agg_kernel(
    const int* __restrict__ bcnt, const int* __restrict__ bdata,
    const float* __restrict__ y, const float* __restrict__ W2,
    const float* __restrict__ b1v, const float* __restrict__ b2v,
    float* __restrict__ z, float* __restrict__ partial)
{
    __shared__ float W2l[DIM * DIM];       // 4 KB
    __shared__ float srow[NPB][DIM];       // 1 KB
    __shared__ int   slist[BCAP];          // 1 KB
    __shared__ int   cnt[NPB], cur[NPB], start[NPB];
    __shared__ float b1l[DIM], b2l[DIM];
    __shared__ float psum[DIM], psq[DIM];

    int tid = threadIdx.x;
    int b = blockIdx.x;
    for (int i = tid; i < DIM * DIM; i += 256) W2l[i] = W2[i];
    if (tid < DIM) {
        b1l[tid] = b1v[tid]; b2l[tid] = b2v[tid];
        psum[tid] = 0.f; psq[tid] = 0.f;
    }
    if (tid < NPB) cnt[tid] = 0;
    __syncthreads();

    int n = bcnt[b]; n = n < BCAP ? n : BCAP;
    int d = -1, ln = 0;
    if (tid < n) {
        d = bdata[b * BCAP + tid];
        ln = d >> 20;
        atomicAdd(&cnt[ln], 1);
    }
    __syncthreads();
    if (tid == 0) {
        int run = 0;
#pragma unroll
        for (int i = 0; i < NPB; ++i) { start[i] = run; cur[i] = run; run += cnt[i]; }
    }
    __syncthreads();
    if (d >= 0) {
        int pos = atomicAdd(&cur[ln], 1);
        slist[pos] = d & 0xFFFFF;
    }
    __syncthreads();

    int myln = tid >> 5;          // node 0..7
    int c = tid & 31;             // column
    int node = b * NPB + myln;
    float acc = y[(long)node * DIM + c] + b1l[c];
    int e0 = start[myln], e1 = start[myln] + cnt[myln];
    for (int e = e0; e < e1; ++e) {
        int src = slist[e];
        acc += y[(long)src * DIM + c];
    }
    srow[myln][c] = fmaxf(acc, 0.f);
    __syncthreads();

    float zv = b2l[c];
#pragma unroll
    for (int k = 0; k < DIM; ++k)
        zv = fmaf(srow[myln][k], W2l[k * DIM + c], zv);
    zv = fmaxf(zv, 0.f);
    z[(long)node * DIM + c] = zv;

    atomicAdd(&psum[c], zv);
    atomicAdd(&psq[c], zv * zv);
    __syncthreads();
    if (tid < 2 * DIM) {
        float v = (tid < DIM) ? psum[tid] : psq[tid - DIM];
        atomicAdd(&partial[(long)(b / PGRP) * 2 * DIM + tid], v);
    }
}

// ---------------- finalize stats -> scale/shift ----------------
__global__ __launch_bounds__(256) void finalize_kernel(
    const float* __restrict__ partial,
    const float* __restrict__ gamma, const float* __restrict__ beta,
    float* __restrict__ ss)
{
    __shared__ float red[256];
    int t = threadIdx.x;
    int c = t & 63;
    int chunk = t >> 6;
    float a = 0.f;
    for (int p = chunk; p < NSLOTS; p += 4) a += partial[(long)p * 64 + c];
    red[t] = a; __syncthreads();
    if (t < 64) red[t] = red[t] + red[t + 64] + red[t + 128] + red[t + 192];
    __syncthreads();
    if (t < DIM) {
        const float invN = 1.0f / (float)N_NODES;
        float S = red[t], Q = red[t + DIM];
        float mu = S * invN;
        float var = Q * invN - mu * mu;
        float scale = gamma[t] * rsqrtf(var + BN_EPS);
        ss[t] = scale;
        ss[DIM + t] = beta[t] - mu * scale;
    }
}

// ------- pool: pooled[g] += affine(z[node]); sorted-batch LDS dedup -------
__global__ __launch_bounds__(256) void pool_kernel(
    const float* __restrict__ z, const int* __restrict__ batch,
    const float* __restrict__ ss, float* __restrict__ pooled)
{
    __shared__ float acc[32][32];
    __shared__ int slot[32];
    __shared__ int segg[32];
    __shared__ int nsegS;
    __shared__ float scl[DIM], shl[DIM];
    int tid = threadIdx.x;
    for (int i = tid; i < 1024; i += 256) ((float*)acc)[i] = 0.f;
    if (tid < DIM) { scl[tid] = ss[tid]; shl[tid] = ss[DIM + tid]; }
    int nodeBase = blockIdx.x * 32;
    if (tid < 32) {
        int nd = nodeBase + tid;
        int gv = batch[nd];
        int flag = (tid == 0) ? 1 : (gv != batch[nd - 1]);
        unsigned long long m = __ballot(flag);
        int s = __popcll(m & ((2ull << tid) - 1ull)) - 1;
        slot[tid] = s;
        if (flag) segg[s] = gv;
        if (tid == 0) nsegS = __popcll(m);
    }
    __syncthreads();

    int ln = tid >> 3;
    int p = tid & 7;
    int node = nodeBase + ln;
    float4 v = *(const float4*)(z + (long)node * DIM + p * 4);
    int c = p * 4;
    v.x = fmaf(v.x, scl[c+0], shl[c+0]);
    v.y = fmaf(v.y, scl[c+1], shl[c+1]);
    v.z = fmaf(v.z, scl[c+2], shl[c+2]);
    v.w = fmaf(v.w, scl[c+3], shl[c+3]);
    int s = slot[ln];
    atomicAdd(&acc[s][c+0], v.x);
    atomicAdd(&acc[s][c+1], v.y);
    atomicAdd(&acc[s][c+2], v.z);
    atomicAdd(&acc[s][c+3], v.w);
    __syncthreads();

    int total = nsegS * 32;
    for (int i = tid; i < total; i += 256) {
        int r = i >> 5, dd = i & 31;
        float val = acc[r][dd];
        if (val != 0.f) atomicAdd(&pooled[(long)segg[r] * DIM + dd], val);
    }
}

// ---------------- final FC + ReLU ----------------
__global__ __launch_bounds__(256) void fc_kernel(
    const float* __restrict__ pooled, const float* __restrict__ Wfc,
    const float* __restrict__ bfc, float* __restrict__ out)
{
    __shared__ float Wl[DIM * OUTD];   // 16 KB
    for (int i = threadIdx.x; i < DIM * OUTD; i += 256) Wl[i] = Wfc[i];
    __syncthreads();
    int t = blockIdx.x * 256 + threadIdx.x;
    if (t >= N_GRAPHS * OUTD) return;
    int g = t >> 7;
    int o = t & (OUTD - 1);
    float acc = bfc[o];
    const float* pr = pooled + (long)g * DIM;
#pragma unroll
    for (int k = 0; k < DIM; ++k) acc += pr[k] * Wl[k * OUTD + o];
    out[t] = fmaxf(acc, 0.f);
}

extern "C" void kernel_launch(void* const* d_in, const int* in_sizes, int n_in,
                              void* d_out, int out_size, void* d_ws, size_t ws_size,
                              hipStream_t stream) {
    const float* x      = (const float*)d_in[0];
    const int*   ei     = (const int*)  d_in[1];
    const int*   batch  = (const int*)  d_in[2];
    const float* W1_0   = (const float*)d_in[3];
    const float* W1_rest= (const float*)d_in[4];
    const float* b1     = (const float*)d_in[5];
    const float* W2     = (const float*)d_in[6];
    const float* b2     = (const float*)d_in[7];
    const float* gamma  = (const float*)d_in[8];
    const float* beta   = (const float*)d_in[9];
    const float* Wfc    = (const float*)d_in[10];
    const float* bfc    = (const float*)d_in[11];
    float* out = (float*)d_out;

    char* ws = (char*)d_ws;
    const size_t nf = (size_t)N_NODES * DIM;                   // 3.2M words
    float* y      = (float*)ws;
    float* z      = y + nf;
    int*   bdata  = (int*)(z + nf);                            // NB*BCAP = 3.2M ints
    float* pooled = (float*)(bdata + (size_t)NB * BCAP);       // 65536
    float* ss     = pooled + (size_t)N_GRAPHS * DIM;           // 5*64
    float* partial= ss + NLAYERS * 2 * DIM;                    // 5*196*64
    int*   bcnt   = (int*)(partial + (size_t)NLAYERS * NSLOTS * 2 * DIM);

    // zero pooled + ss + partials (contiguous) and bcnt
    hipMemsetAsync(pooled, 0,
        ((size_t)N_GRAPHS * DIM + NLAYERS * 2 * DIM +
         (size_t)NLAYERS * NSLOTS * 2 * DIM) * sizeof(float), stream);
    hipMemsetAsync(bcnt, 0, (size_t)NB * sizeof(int), stream);

    const int edgeBlocks = (N_EDGES + 255) / 256;
    const int grpBlocks = (N_NODES * 8) / 256;                 // 3125

    bfill_kernel<<<edgeBlocks, 256, 0, stream>>>(ei, bcnt, bdata);

    const float* hin = x;
    for (int i = 0; i < NLAYERS; ++i) {
        if (i == 0) {
            gemm1f_kernel<NFEAT, false><<<grpBlocks, 256, 0, stream>>>(
                hin, W1_0, nullptr, y);
        } else {
            gemm1f_kernel<DIM, true><<<grpBlocks, 256, 0, stream>>>(
                hin, W1_rest + (size_t)(i - 1) * DIM * DIM,
                ss + (i - 1) * 2 * DIM, y);
        }
        bucket_agg_kernel<<<NB, 256, 0, stream>>>(
            bcnt, bdata, y, W2 + (size_t)i * DIM * DIM,
            b1 + i * DIM, b2 + i * DIM, z,
            partial + (size_t)i * NSLOTS * 2 * DIM);
        finalize_kernel<<<1, 256, 0, stream>>>(
            partial + (size_t)i * NSLOTS * 2 * DIM,
            gamma + i * DIM, beta + i * DIM, ss + i * 2 * DIM);
        hin = z;
    }

    pool_kernel<<<N_NODES / 32, 256, 0, stream>>>(
        z, batch, ss + (NLAYERS - 1) * 2 * DIM, pooled);
    fc_kernel<<<(N_GRAPHS * OUTD) / 256, 256, 0, stream>>>(pooled, Wfc, bfc, out);
}

// Round 5
// 625.494 us; speedup vs baseline: 1.2353x; 1.2353x over previous
//
#include <hip/hip_runtime.h>

#define N_NODES 100000
#define N_EDGES 1600000
#define N_GRAPHS 2048
#define NFEAT 78
#define DIM 32
#define NLAYERS 5
#define OUTD 128
#define BN_EPS 1e-5f
#define SCAN_BLK 1024
#define NB 3125        // buckets = N_NODES/32
#define NPB 32         // nodes per bucket
#define NSUB 8         // sub-tails per bucket (sharded by blockIdx&7 ~ XCD)
#define SUBCAP 128     // per-sub capacity (mean 64, ~8 sigma)

// ---------- bucket fill: XCD-sharded tails ----------
__global__ __launch_bounds__(256) void bfill_kernel(
    const int* __restrict__ ei, int* __restrict__ bcnt, int* __restrict__ bdata)
{
    int e = blockIdx.x * 256 + threadIdx.x;
    if (e >= N_EDGES) return;
    int sub = blockIdx.x & (NSUB - 1);
    int src = ei[e];
    int dst = ei[N_EDGES + e];
    int b = dst >> 5;
    int pos = atomicAdd(&bcnt[b * NSUB + sub], 1);
    if (pos < SUBCAP)
        bdata[b * (NSUB * SUBCAP) + sub * SUBCAP + pos] = src | ((dst & 31) << 20);
}

// ---------- per-node counts via LDS (one block per bucket) ----------
__global__ __launch_bounds__(256) void pcount_kernel(
    const int* __restrict__ bcnt, const int* __restrict__ bdata,
    int* __restrict__ counts)
{
    __shared__ int cnt[NPB];
    __shared__ int ns[NSUB];
    int b = blockIdx.x;
    int tid = threadIdx.x;
    if (tid < NPB) cnt[tid] = 0;
    if (tid < NSUB) {
        int v = bcnt[b * NSUB + tid];
        ns[tid] = v < SUBCAP ? v : SUBCAP;
    }
    __syncthreads();
    for (int i = tid; i < NSUB * SUBCAP; i += 256) {
        int sub = i >> 7, pos = i & (SUBCAP - 1);
        if (pos < ns[sub])
            atomicAdd(&cnt[bdata[b * (NSUB * SUBCAP) + i] >> 20], 1);
    }
    __syncthreads();
    if (tid < NPB) counts[b * NPB + tid] = cnt[tid];
}

// ---------- hierarchical exclusive scan over counts (100K) ----------
__global__ __launch_bounds__(256) void scan_a_kernel(
    const int* __restrict__ counts, int* __restrict__ blockSums)
{
    __shared__ int sd[256];
    int tid = threadIdx.x;
    int base = blockIdx.x * SCAN_BLK + tid * 4;
    int s = 0;
#pragma unroll
    for (int k = 0; k < 4; ++k) {
        int i = base + k;
        if (i < N_NODES) s += counts[i];
    }
    sd[tid] = s; __syncthreads();
    for (int off = 128; off > 0; off >>= 1) {
        if (tid < off) sd[tid] += sd[tid + off];
        __syncthreads();
    }
    if (tid == 0) blockSums[blockIdx.x] = sd[0];
}

__global__ __launch_bounds__(128) void scan_b_kernel(int* blockSums, int nsb)
{
    __shared__ int sd[128];
    int tid = threadIdx.x;
    int v = (tid < nsb) ? blockSums[tid] : 0;
    sd[tid] = v; __syncthreads();
    for (int off = 1; off < 128; off <<= 1) {
        int a = (tid >= off) ? sd[tid - off] : 0;
        __syncthreads();
        sd[tid] += a;
        __syncthreads();
    }
    if (tid < nsb) blockSums[tid] = sd[tid] - v;   // exclusive
}

__global__ __launch_bounds__(256) void scan_c_kernel(
    const int* __restrict__ counts, const int* __restrict__ blockOffs,
    int* __restrict__ row_ptr)
{
    __shared__ int sc[256];
    int tid = threadIdx.x;
    int base = blockIdx.x * SCAN_BLK + tid * 4;
    int c[4]; int ts = 0;
#pragma unroll
    for (int k = 0; k < 4; ++k) {
        int i = base + k;
        c[k] = (i < N_NODES) ? counts[i] : 0;
        ts += c[k];
    }
    sc[tid] = ts; __syncthreads();
    for (int off = 1; off < 256; off <<= 1) {
        int a = (tid >= off) ? sc[tid - off] : 0;
        __syncthreads();
        sc[tid] += a;
        __syncthreads();
    }
    int run = blockOffs[blockIdx.x] + sc[tid] - ts;
#pragma unroll
    for (int k = 0; k < 4; ++k) {
        int i = base + k;
        if (i < N_NODES) { row_ptr[i] = run; run += c[k]; }
    }
    if (blockIdx.x == 0 && tid == 0) row_ptr[N_NODES] = N_EDGES;
}

// ---------- final CSR fill via LDS cursors (one block per bucket) ----------
__global__ __launch_bounds__(256) void cfill_kernel(
    const int* __restrict__ bcnt, const int* __restrict__ bdata,
    const int* __restrict__ row_ptr, int* __restrict__ edge_src)
{
    __shared__ int cur[NPB];
    __shared__ int ns[NSUB];
    int b = blockIdx.x;
    int tid = threadIdx.x;
    if (tid < NPB) cur[tid] = row_ptr[b * NPB + tid];
    if (tid < NSUB) {
        int v = bcnt[b * NSUB + tid];
        ns[tid] = v < SUBCAP ? v : SUBCAP;
    }
    __syncthreads();
    for (int i = tid; i < NSUB * SUBCAP; i += 256) {
        int sub = i >> 7, pos = i & (SUBCAP - 1);
        if (pos < ns[sub]) {
            int d = bdata[b * (NSUB * SUBCAP) + i];
            int p = atomicAdd(&cur[d >> 20], 1);
            edge_src[p] = d & 0xFFFFF;
        }
    }
}

// ---------- GEMM1 (8 threads/row): y = affine(h) @ W1 ----------
template<int K, bool AFF>
__global__ __launch_bounds__(256) void gemm1f_kernel(
    const float* __restrict__ h, const float* __restrict__ W,
    const float* __restrict__ ss, float* __restrict__ y)
{
    __shared__ float Wl[K * DIM];
    __shared__ float scl[DIM], shl[DIM];
    for (int i = threadIdx.x; i < K * DIM; i += 256) Wl[i] = W[i];
    if (AFF && threadIdx.x < DIM) {
        scl[threadIdx.x] = ss[threadIdx.x];
        shl[threadIdx.x] = ss[DIM + threadIdx.x];
    }
    __syncthreads();

    int t = blockIdx.x * 256 + threadIdx.x;
    int row = t >> 3;
    int c0 = (t & 7) * 4;

    float4 acc = make_float4(0.f, 0.f, 0.f, 0.f);
    const float* hr = h + (long)row * K;
    for (int k = 0; k < K; ++k) {
        float xv = hr[k];
        if (AFF) xv = fmaf(xv, scl[k], shl[k]);
        acc.x += xv * Wl[k * DIM + c0 + 0];
        acc.y += xv * Wl[k * DIM + c0 + 1];
        acc.z += xv * Wl[k * DIM + c0 + 2];
        acc.w += xv * Wl[k * DIM + c0 + 3];
    }
    *(float4*)(y + (long)row * DIM + c0) = acc;
}

// ------- aggregate (CSR gather): s[i] = y[i] + b1 + sum_in y[src] -------
__global__ __launch_bounds__(256) void aggregate_kernel(
    const int* __restrict__ row_ptr, const int* __restrict__ edge_src,
    const float* __restrict__ y, const float* __restrict__ b,
    float* __restrict__ s)
{
    int t = blockIdx.x * 256 + threadIdx.x;
    int node = t >> 3;
    int p = t & 7;

    float4 acc = *(const float4*)(y + (long)node * DIM + p * 4);
    float4 bb = *(const float4*)(b + p * 4);
    acc.x += bb.x; acc.y += bb.y; acc.z += bb.z; acc.w += bb.w;

    int beg = row_ptr[node];
    int end = row_ptr[node + 1];
    for (int e = beg; e < end; ++e) {
        int src = edge_src[e];
        float4 v = *(const float4*)(y + (long)src * DIM + p * 4);
        acc.x += v.x; acc.y += v.y; acc.z += v.z; acc.w += v.w;
    }
    *(float4*)(s + (long)node * DIM + p * 4) = acc;
}

// ------- GEMM2: z = relu(relu(s) @ W2 + b2); per-block partial stats -------
__global__ __launch_bounds__(256) void gemm2_kernel(
    const float* __restrict__ s, const float* __restrict__ W2,
    const float* __restrict__ b2, float* __restrict__ z,
    float* __restrict__ partial, int n)
{
    __shared__ float Wl[DIM * DIM];
    __shared__ float bl[DIM];
    __shared__ float psum[4][DIM];
    __shared__ float psq[4][DIM];
    for (int i = threadIdx.x; i < DIM * DIM; i += 256) Wl[i] = W2[i];
    if (threadIdx.x < DIM) bl[threadIdx.x] = b2[threadIdx.x];
    __syncthreads();

    int row = blockIdx.x * 256 + threadIdx.x;
    float zv[DIM];
    if (row < n) {
        float a[DIM];
        const float4* sv = (const float4*)(s + (long)row * DIM);
#pragma unroll
        for (int q = 0; q < DIM / 4; ++q) {
            float4 v = sv[q];
            a[q*4+0] = fmaxf(v.x, 0.f);
            a[q*4+1] = fmaxf(v.y, 0.f);
            a[q*4+2] = fmaxf(v.z, 0.f);
            a[q*4+3] = fmaxf(v.w, 0.f);
        }
#pragma unroll
        for (int j = 0; j < DIM; ++j) zv[j] = bl[j];
#pragma unroll
        for (int k = 0; k < DIM; ++k) {
#pragma unroll
            for (int j = 0; j < DIM; ++j) zv[j] += a[k] * Wl[k * DIM + j];
        }
#pragma unroll
        for (int j = 0; j < DIM; ++j) zv[j] = fmaxf(zv[j], 0.f);
        float4* zp = (float4*)(z + (long)row * DIM);
#pragma unroll
        for (int q = 0; q < DIM / 4; ++q)
            zp[q] = make_float4(zv[q*4+0], zv[q*4+1], zv[q*4+2], zv[q*4+3]);
    } else {
#pragma unroll
        for (int j = 0; j < DIM; ++j) zv[j] = 0.f;
    }

    float sq[DIM];
#pragma unroll
    for (int j = 0; j < DIM; ++j) sq[j] = zv[j] * zv[j];
#pragma unroll
    for (int off = 1; off < 64; off <<= 1) {
#pragma unroll
        for (int j = 0; j < DIM; ++j) {
            zv[j] += __shfl_xor(zv[j], off, 64);
            sq[j] += __shfl_xor(sq[j], off, 64);
        }
    }
    int wid = threadIdx.x >> 6, lane = threadIdx.x & 63;
    if (lane == 0) {
#pragma unroll
        for (int j = 0; j < DIM; ++j) { psum[wid][j] = zv[j]; psq[wid][j] = sq[j]; }
    }
    __syncthreads();
    if (threadIdx.x < DIM) {
        int c = threadIdx.x;
        float a = psum[0][c] + psum[1][c] + psum[2][c] + psum[3][c];
        float q = psq[0][c] + psq[1][c] + psq[2][c] + psq[3][c];
        partial[(long)blockIdx.x * 2 * DIM + c] = a;
        partial[(long)blockIdx.x * 2 * DIM + DIM + c] = q;
    }
}

// ---------------- finalize stats -> scale/shift ----------------
__global__ __launch_bounds__(256) void finalize_kernel(
    const float* __restrict__ partial, int nparts,
    const float* __restrict__ gamma, const float* __restrict__ beta,
    float* __restrict__ ss)
{
    __shared__ float red[256];
    int t = threadIdx.x;
    int c = t & 63;
    int chunk = t >> 6;
    float a = 0.f;
    for (int p = chunk; p < nparts; p += 4) a += partial[(long)p * 64 + c];
    red[t] = a; __syncthreads();
    if (t < 64) red[t] = red[t] + red[t+64] + red[t+128] + red[t+192];
    __syncthreads();
    if (t < DIM) {
        const float invN = 1.0f / (float)N_NODES;
        float S = red[t], Q = red[t + DIM];
        float mu = S * invN;
        float var = Q * invN - mu * mu;
        float scale = gamma[t] * rsqrtf(var + BN_EPS);
        ss[t] = scale;
        ss[DIM + t] = beta[t] - mu * scale;
    }
}

// ------- pool: pooled[g] += affine(z[node]); sorted-batch LDS dedup -------
__global__ __launch_bounds__(256) void pool_kernel(
    const float* __restrict__ z, const int* __restrict__ batch,
    const float* __restrict__ ss, float* __restrict__ pooled)
{
    __shared__ float acc[32][32];
    __shared__ int slot[32];
    __shared__ int segg[32];
    __shared__ int nsegS;
    __shared__ float scl[DIM], shl[DIM];
    int tid = threadIdx.x;
    for (int i = tid; i < 1024; i += 256) ((float*)acc)[i] = 0.f;
    if (tid < DIM) { scl[tid] = ss[tid]; shl[tid] = ss[DIM + tid]; }
    int nodeBase = blockIdx.x * 32;
    if (tid < 32) {
        int nd = nodeBase + tid;
        int gv = batch[nd];
        int flag = (tid == 0) ? 1 : (gv != batch[nd - 1]);
        unsigned long long m = __ballot(flag);
        int s = __popcll(m & ((2ull << tid) - 1ull)) - 1;
        slot[tid] = s;
        if (flag) segg[s] = gv;
        if (tid == 0) nsegS = __popcll(m);
    }
    __syncthreads();

    int ln = tid >> 3;
    int p = tid & 7;
    int node = nodeBase + ln;
    float4 v = *(const float4*)(z + (long)node * DIM + p * 4);
    int c = p * 4;
    v.x = fmaf(v.x, scl[c+0], shl[c+0]);
    v.y = fmaf(v.y, scl[c+1], shl[c+1]);
    v.z = fmaf(v.z, scl[c+2], shl[c+2]);
    v.w = fmaf(v.w, scl[c+3], shl[c+3]);
    int s = slot[ln];
    atomicAdd(&acc[s][c+0], v.x);
    atomicAdd(&acc[s][c+1], v.y);
    atomicAdd(&acc[s][c+2], v.z);
    atomicAdd(&acc[s][c+3], v.w);
    __syncthreads();

    int total = nsegS * 32;
    for (int i = tid; i < total; i += 256) {
        int r = i >> 5, dd = i & 31;
        float val = acc[r][dd];
        if (val != 0.f) atomicAdd(&pooled[(long)segg[r] * DIM + dd], val);
    }
}

// ---------------- final FC + ReLU ----------------
__global__ __launch_bounds__(256) void fc_kernel(
    const float* __restrict__ pooled, const float* __restrict__ Wfc,
    const float* __restrict__ bfc, float* __restrict__ out)
{
    __shared__ float Wl[DIM * OUTD];   // 16 KB
    for (int i = threadIdx.x; i < DIM * OUTD; i += 256) Wl[i] = Wfc[i];
    __syncthreads();
    int t = blockIdx.x * 256 + threadIdx.x;
    if (t >= N_GRAPHS * OUTD) return;
    int g = t >> 7;
    int o = t & (OUTD - 1);
    float acc = bfc[o];
    const float* pr = pooled + (long)g * DIM;
#pragma unroll
    for (int k = 0; k < DIM; ++k) acc += pr[k] * Wl[k * OUTD + o];
    out[t] = fmaxf(acc, 0.f);
}

extern "C" void kernel_launch(void* const* d_in, const int* in_sizes, int n_in,
                              void* d_out, int out_size, void* d_ws, size_t ws_size,
                              hipStream_t stream) {
    const float* x      = (const float*)d_in[0];
    const int*   ei     = (const int*)  d_in[1];
    const int*   batch  = (const int*)  d_in[2];
    const float* W1_0   = (const float*)d_in[3];
    const float* W1_rest= (const float*)d_in[4];
    const float* b1     = (const float*)d_in[5];
    const float* W2     = (const float*)d_in[6];
    const float* b2     = (const float*)d_in[7];
    const float* gamma  = (const float*)d_in[8];
    const float* beta   = (const float*)d_in[9];
    const float* Wfc    = (const float*)d_in[10];
    const float* bfc    = (const float*)d_in[11];
    float* out = (float*)d_out;

    char* ws = (char*)d_ws;
    const size_t nf = (size_t)N_NODES * DIM;                   // 3.2M words
    float* y      = (float*)ws;
    float* s      = y + nf;
    float* z      = s + nf;          // overlaid with bdata (both 3.2M words)
    int*   bdata  = (int*)z;         // NB*NSUB*SUBCAP = 3,200,000 ints exactly
    float* pooled = z + nf;                                    // 65536
    float* ss     = pooled + (size_t)N_GRAPHS * DIM;           // 5*64
    float* partial= ss + NLAYERS * 2 * DIM;                    // 391*64
    const int rowBlocks = (N_NODES + 255) / 256;               // 391
    int*   counts = (int*)(partial + (size_t)rowBlocks * 2 * DIM);
    int*   row_ptr= counts + N_NODES;                          // 100001
    int*   blockSums = row_ptr + (N_NODES + 1);                // 128
    int*   bcnt   = blockSums + 128;                           // NB*NSUB = 25000
    int*   edge_src = bcnt + NB * NSUB;                        // 1.6M

    hipMemsetAsync(pooled, 0, (size_t)N_GRAPHS * DIM * sizeof(float), stream);
    hipMemsetAsync(bcnt, 0, (size_t)NB * NSUB * sizeof(int), stream);

    const int edgeBlocks = (N_EDGES + 255) / 256;
    const int grpBlocks = (N_NODES * 8) / 256;                 // 3125
    const int nsb = (N_NODES + SCAN_BLK - 1) / SCAN_BLK;       // 98

    // CSR build (bucketed, XCD-sharded tails)
    bfill_kernel<<<edgeBlocks, 256, 0, stream>>>(ei, bcnt, bdata);
    pcount_kernel<<<NB, 256, 0, stream>>>(bcnt, bdata, counts);
    scan_a_kernel<<<nsb, 256, 0, stream>>>(counts, blockSums);
    scan_b_kernel<<<1, 128, 0, stream>>>(blockSums, nsb);
    scan_c_kernel<<<nsb, 256, 0, stream>>>(counts, blockSums, row_ptr);
    cfill_kernel<<<NB, 256, 0, stream>>>(bcnt, bdata, row_ptr, edge_src);

    const float* hin = x;
    for (int i = 0; i < NLAYERS; ++i) {
        if (i == 0) {
            gemm1f_kernel<NFEAT, false><<<grpBlocks, 256, 0, stream>>>(
                hin, W1_0, nullptr, y);
        } else {
            gemm1f_kernel<DIM, true><<<grpBlocks, 256, 0, stream>>>(
                hin, W1_rest + (size_t)(i - 1) * DIM * DIM,
                ss + (i - 1) * 2 * DIM, y);
        }
        aggregate_kernel<<<grpBlocks, 256, 0, stream>>>(
            row_ptr, edge_src, y, b1 + i * DIM, s);
        gemm2_kernel<<<rowBlocks, 256, 0, stream>>>(
            s, W2 + (size_t)i * DIM * DIM, b2 + i * DIM, z, partial, N_NODES);
        finalize_kernel<<<1, 256, 0, stream>>>(
            partial, rowBlocks, gamma + i * DIM, beta + i * DIM,
            ss + i * 2 * DIM);
        hin = z;
    }

    pool_kernel<<<N_NODES / 32, 256, 0, stream>>>(
        z, batch, ss + (NLAYERS - 1) * 2 * DIM, pooled);
    fc_kernel<<<(N_GRAPHS * OUTD) / 256, 256, 0, stream>>>(pooled, Wfc, bfc, out);
}

// Round 6
// 452.747 us; speedup vs baseline: 1.7067x; 1.3816x over previous
//
#include <hip/hip_runtime.h>

#define N_NODES 100000
#define N_EDGES 1600000
#define N_GRAPHS 2048
#define NFEAT 78
#define DIM 32
#define NLAYERS 5
#define OUTD 128
#define BN_EPS 1e-5f
#define SCAN_BLK 1024
#define NB 3125        // buckets = N_NODES/32
#define NPB 32         // nodes per bucket
#define NSUB 8         // sub-tails per bucket (sharded by blockIdx&7 ~ XCD)
#define SUBCAP 128     // per-sub capacity (mean 64, ~8 sigma)
#define NSLOTS2 ((NB + 63) / 64)   // 49 partial-stats slots

// ---------- bucket fill: XCD-sharded tails ----------
__global__ __launch_bounds__(256) void bfill_kernel(
    const int* __restrict__ ei, int* __restrict__ bcnt, int* __restrict__ bdata)
{
    int e = blockIdx.x * 256 + threadIdx.x;
    if (e >= N_EDGES) return;
    int sub = blockIdx.x & (NSUB - 1);
    int src = ei[e];
    int dst = ei[N_EDGES + e];
    int b = dst >> 5;
    int pos = atomicAdd(&bcnt[b * NSUB + sub], 1);
    if (pos < SUBCAP)
        bdata[b * (NSUB * SUBCAP) + sub * SUBCAP + pos] = src | ((dst & 31) << 20);
}

// ---------- per-node counts via LDS (one block per bucket) ----------
__global__ __launch_bounds__(256) void pcount_kernel(
    const int* __restrict__ bcnt, const int* __restrict__ bdata,
    int* __restrict__ counts)
{
    __shared__ int cnt[NPB];
    __shared__ int ns[NSUB];
    int b = blockIdx.x;
    int tid = threadIdx.x;
    if (tid < NPB) cnt[tid] = 0;
    if (tid < NSUB) {
        int v = bcnt[b * NSUB + tid];
        ns[tid] = v < SUBCAP ? v : SUBCAP;
    }
    __syncthreads();
    for (int i = tid; i < NSUB * SUBCAP; i += 256) {
        int sub = i >> 7, pos = i & (SUBCAP - 1);
        if (pos < ns[sub])
            atomicAdd(&cnt[bdata[b * (NSUB * SUBCAP) + i] >> 20], 1);
    }
    __syncthreads();
    if (tid < NPB) counts[b * NPB + tid] = cnt[tid];
}

// ---------- hierarchical exclusive scan over counts (100K) ----------
__global__ __launch_bounds__(256) void scan_a_kernel(
    const int* __restrict__ counts, int* __restrict__ blockSums)
{
    __shared__ int sd[256];
    int tid = threadIdx.x;
    int base = blockIdx.x * SCAN_BLK + tid * 4;
    int s = 0;
#pragma unroll
    for (int k = 0; k < 4; ++k) {
        int i = base + k;
        if (i < N_NODES) s += counts[i];
    }
    sd[tid] = s; __syncthreads();
    for (int off = 128; off > 0; off >>= 1) {
        if (tid < off) sd[tid] += sd[tid + off];
        __syncthreads();
    }
    if (tid == 0) blockSums[blockIdx.x] = sd[0];
}

__global__ __launch_bounds__(128) void scan_b_kernel(int* blockSums, int nsb)
{
    __shared__ int sd[128];
    int tid = threadIdx.x;
    int v = (tid < nsb) ? blockSums[tid] : 0;
    sd[tid] = v; __syncthreads();
    for (int off = 1; off < 128; off <<= 1) {
        int a = (tid >= off) ? sd[tid - off] : 0;
        __syncthreads();
        sd[tid] += a;
        __syncthreads();
    }
    if (tid < nsb) blockSums[tid] = sd[tid] - v;   // exclusive
}

__global__ __launch_bounds__(256) void scan_c_kernel(
    const int* __restrict__ counts, const int* __restrict__ blockOffs,
    int* __restrict__ row_ptr)
{
    __shared__ int sc[256];
    int tid = threadIdx.x;
    int base = blockIdx.x * SCAN_BLK + tid * 4;
    int c[4]; int ts = 0;
#pragma unroll
    for (int k = 0; k < 4; ++k) {
        int i = base + k;
        c[k] = (i < N_NODES) ? counts[i] : 0;
        ts += c[k];
    }
    sc[tid] = ts; __syncthreads();
    for (int off = 1; off < 256; off <<= 1) {
        int a = (tid >= off) ? sc[tid - off] : 0;
        __syncthreads();
        sc[tid] += a;
        __syncthreads();
    }
    int run = blockOffs[blockIdx.x] + sc[tid] - ts;
#pragma unroll
    for (int k = 0; k < 4; ++k) {
        int i = base + k;
        if (i < N_NODES) { row_ptr[i] = run; run += c[k]; }
    }
    if (blockIdx.x == 0 && tid == 0) row_ptr[N_NODES] = N_EDGES;
}

// ---------- final CSR fill via LDS cursors (one block per bucket) ----------
__global__ __launch_bounds__(256) void cfill_kernel(
    const int* __restrict__ bcnt, const int* __restrict__ bdata,
    const int* __restrict__ row_ptr, int* __restrict__ edge_src)
{
    __shared__ int cur[NPB];
    __shared__ int ns[NSUB];
    int b = blockIdx.x;
    int tid = threadIdx.x;
    if (tid < NPB) cur[tid] = row_ptr[b * NPB + tid];
    if (tid < NSUB) {
        int v = bcnt[b * NSUB + tid];
        ns[tid] = v < SUBCAP ? v : SUBCAP;
    }
    __syncthreads();
    for (int i = tid; i < NSUB * SUBCAP; i += 256) {
        int sub = i >> 7, pos = i & (SUBCAP - 1);
        if (pos < ns[sub]) {
            int d = bdata[b * (NSUB * SUBCAP) + i];
            int p = atomicAdd(&cur[d >> 20], 1);
            edge_src[p] = d & 0xFFFFF;
        }
    }
}

// ---------- GEMM1 layer0 only (8 threads/row): y0 = x @ W1_0 ----------
__global__ __launch_bounds__(256) void gemm1_kernel(
    const float* __restrict__ h, const float* __restrict__ W,
    float* __restrict__ y)
{
    __shared__ float Wl[NFEAT * DIM];   // 9.75 KB
    for (int i = threadIdx.x; i < NFEAT * DIM; i += 256) Wl[i] = W[i];
    __syncthreads();

    int t = blockIdx.x * 256 + threadIdx.x;
    int row = t >> 3;
    int c0 = (t & 7) * 4;

    float4 acc = make_float4(0.f, 0.f, 0.f, 0.f);
    const float* hr = h + (long)row * NFEAT;
    for (int k = 0; k < NFEAT; ++k) {
        float xv = hr[k];
        acc.x += xv * Wl[k * DIM + c0 + 0];
        acc.y += xv * Wl[k * DIM + c0 + 1];
        acc.z += xv * Wl[k * DIM + c0 + 2];
        acc.w += xv * Wl[k * DIM + c0 + 3];
    }
    *(float4*)(y + (long)row * DIM + c0) = acc;
}

// ---- fused layer: gather zsum -> [@W1'+ (deg+1)c + b1] -> relu -> @W2+b2
//      -> relu -> zout + BN partial stats.  One block = 32 nodes. ----
template<bool MM>
__global__ __launch_bounds__(256) void layer_kernel(
    const int* __restrict__ row_ptr, const int* __restrict__ edge_src,
    const float* __restrict__ zin, const float* __restrict__ W1p,
    const float* __restrict__ cvec, const float* __restrict__ b1v,
    const float* __restrict__ W2, const float* __restrict__ b2v,
    float* __restrict__ zout, float* __restrict__ partial)
{
    __shared__ float W1l[DIM * DIM];       // 4 KB (used iff MM)
    __shared__ float W2l[DIM * DIM];       // 4 KB
    __shared__ float zs[NPB][36];          // 4.5 KB (pad 36: 16B-aligned rows)
    __shared__ float srow[NPB][36];        // 4.5 KB
    __shared__ float b1l[DIM], b2l[DIM], cl[DIM];
    __shared__ float psum[DIM], psq[DIM];
    __shared__ int degl[NPB];

    int tid = threadIdx.x;
    if (MM) for (int i = tid; i < DIM * DIM; i += 256) W1l[i] = W1p[i];
    for (int i = tid; i < DIM * DIM; i += 256) W2l[i] = W2[i];
    if (tid < DIM) {
        b1l[tid] = b1v[tid]; b2l[tid] = b2v[tid];
        cl[tid] = MM ? cvec[tid] : 0.f;
        psum[tid] = 0.f; psq[tid] = 0.f;
    }
    __syncthreads();

    int ln = tid >> 3, p = tid & 7;
    int c0 = p * 4;
    long node = (long)blockIdx.x * NPB + ln;
    int beg = row_ptr[node], end = row_ptr[node + 1];
    if (p == 0) degl[ln] = end - beg;

    // phase 1: gather zsum (self + in-neighbors), 8 threads/node, float4 each
    float4 acc = *(const float4*)(zin + node * DIM + c0);
    for (int e = beg; e < end; ++e) {
        int s = edge_src[e];
        float4 v = *(const float4*)(zin + (long)s * DIM + c0);
        acc.x += v.x; acc.y += v.y; acc.z += v.z; acc.w += v.w;
    }
    *(float4*)&zs[ln][c0] = acc;
    __syncthreads();

    // phase 2: s = zsum@W1' + (deg+1)*c + b1  (or zsum + b1), relu
    float sv[4];
    if (MM) {
        sv[0] = sv[1] = sv[2] = sv[3] = 0.f;
#pragma unroll
        for (int k = 0; k < DIM; ++k) {
            float zk = zs[ln][k];
            sv[0] = fmaf(zk, W1l[k * DIM + c0 + 0], sv[0]);
            sv[1] = fmaf(zk, W1l[k * DIM + c0 + 1], sv[1]);
            sv[2] = fmaf(zk, W1l[k * DIM + c0 + 2], sv[2]);
            sv[3] = fmaf(zk, W1l[k * DIM + c0 + 3], sv[3]);
        }
        float dp1 = (float)(degl[ln] + 1);
#pragma unroll
        for (int j = 0; j < 4; ++j)
            sv[j] = fmaf(dp1, cl[c0 + j], sv[j]) + b1l[c0 + j];
    } else {
#pragma unroll
        for (int j = 0; j < 4; ++j) sv[j] = zs[ln][c0 + j] + b1l[c0 + j];
    }
    float4 srw = make_float4(fmaxf(sv[0], 0.f), fmaxf(sv[1], 0.f),
                             fmaxf(sv[2], 0.f), fmaxf(sv[3], 0.f));
    *(float4*)&srow[ln][c0] = srw;
    __syncthreads();

    // phase 3: z = relu(srow@W2 + b2), write out + stats
    float zv[4] = { b2l[c0 + 0], b2l[c0 + 1], b2l[c0 + 2], b2l[c0 + 3] };
#pragma unroll
    for (int k = 0; k < DIM; ++k) {
        float sk = srow[ln][k];
        zv[0] = fmaf(sk, W2l[k * DIM + c0 + 0], zv[0]);
        zv[1] = fmaf(sk, W2l[k * DIM + c0 + 1], zv[1]);
        zv[2] = fmaf(sk, W2l[k * DIM + c0 + 2], zv[2]);
        zv[3] = fmaf(sk, W2l[k * DIM + c0 + 3], zv[3]);
    }
#pragma unroll
    for (int j = 0; j < 4; ++j) zv[j] = fmaxf(zv[j], 0.f);
    *(float4*)(zout + node * DIM + c0) = make_float4(zv[0], zv[1], zv[2], zv[3]);

    float sq[4];
#pragma unroll
    for (int j = 0; j < 4; ++j) sq[j] = zv[j] * zv[j];
    // reduce across the 8 nodes of this wave (lanes stride 8)
#pragma unroll
    for (int off = 8; off < 64; off <<= 1) {
#pragma unroll
        for (int j = 0; j < 4; ++j) {
            zv[j] += __shfl_xor(zv[j], off, 64);
            sq[j] += __shfl_xor(sq[j], off, 64);
        }
    }
    if ((tid & 63) < 8) {
#pragma unroll
        for (int j = 0; j < 4; ++j) {
            atomicAdd(&psum[c0 + j], zv[j]);
            atomicAdd(&psq[c0 + j], sq[j]);
        }
    }
    __syncthreads();
    if (tid < 2 * DIM) {
        float v = (tid < DIM) ? psum[tid] : psq[tid - DIM];
        atomicAdd(&partial[(long)(blockIdx.x >> 6) * 2 * DIM + tid], v);
    }
}

// ------ finalize: stats -> scale/shift; fold next layer's W1' and c ------
__global__ __launch_bounds__(256) void finalize_kernel(
    const float* __restrict__ partial,
    const float* __restrict__ gamma, const float* __restrict__ beta,
    float* __restrict__ ss, const float* W1next,
    float* __restrict__ W1p, float* __restrict__ cvec)
{
    __shared__ float red[256];
    __shared__ float sscl[DIM], sshl[DIM];
    int t = threadIdx.x;
    int c = t & 63;
    int chunk = t >> 6;
    float a = 0.f;
    for (int p = chunk; p < NSLOTS2; p += 4) a += partial[(long)p * 64 + c];
    red[t] = a; __syncthreads();
    if (t < 64) red[t] = red[t] + red[t + 64] + red[t + 128] + red[t + 192];
    __syncthreads();
    if (t < DIM) {
        const float invN = 1.0f / (float)N_NODES;
        float S = red[t], Q = red[t + DIM];
        float mu = S * invN;
        float var = Q * invN - mu * mu;
        float scale = gamma[t] * rsqrtf(var + BN_EPS);
        float shift = beta[t] - mu * scale;
        ss[t] = scale; ss[DIM + t] = shift;
        sscl[t] = scale; sshl[t] = shift;
    }
    __syncthreads();
    if (W1next) {
        for (int i = t; i < DIM * DIM; i += 256)
            W1p[i] = sscl[i >> 5] * W1next[i];
        if (t < DIM) {
            float cv = 0.f;
            for (int k = 0; k < DIM; ++k)
                cv += sshl[k] * W1next[k * DIM + t];
            cvec[t] = cv;
        }
    }
}

// ------- pool: pooled[g] += affine(z[node]); sorted-batch LDS dedup -------
__global__ __launch_bounds__(256) void pool_kernel(
    const float* __restrict__ z, const int* __restrict__ batch,
    const float* __restrict__ ss, float* __restrict__ pooled)
{
    __shared__ float acc[32][32];
    __shared__ int slot[32];
    __shared__ int segg[32];
    __shared__ int nsegS;
    __shared__ float scl[DIM], shl[DIM];
    int tid = threadIdx.x;
    for (int i = tid; i < 1024; i += 256) ((float*)acc)[i] = 0.f;
    if (tid < DIM) { scl[tid] = ss[tid]; shl[tid] = ss[DIM + tid]; }
    int nodeBase = blockIdx.x * 32;
    if (tid < 32) {
        int nd = nodeBase + tid;
        int gv = batch[nd];
        int flag = (tid == 0) ? 1 : (gv != batch[nd - 1]);
        unsigned long long m = __ballot(flag);
        int s = __popcll(m & ((2ull << tid) - 1ull)) - 1;
        slot[tid] = s;
        if (flag) segg[s] = gv;
        if (tid == 0) nsegS = __popcll(m);
    }
    __syncthreads();

    int ln = tid >> 3;
    int p = tid & 7;
    int node = nodeBase + ln;
    float4 v = *(const float4*)(z + (long)node * DIM + p * 4);
    int c = p * 4;
    v.x = fmaf(v.x, scl[c+0], shl[c+0]);
    v.y = fmaf(v.y, scl[c+1], shl[c+1]);
    v.z = fmaf(v.z, scl[c+2], shl[c+2]);
    v.w = fmaf(v.w, scl[c+3], shl[c+3]);
    int s = slot[ln];
    atomicAdd(&acc[s][c+0], v.x);
    atomicAdd(&acc[s][c+1], v.y);
    atomicAdd(&acc[s][c+2], v.z);
    atomicAdd(&acc[s][c+3], v.w);
    __syncthreads();

    int total = nsegS * 32;
    for (int i = tid; i < total; i += 256) {
        int r = i >> 5, dd = i & 31;
        float val = acc[r][dd];
        if (val != 0.f) atomicAdd(&pooled[(long)segg[r] * DIM + dd], val);
    }
}

// ---------------- final FC + ReLU ----------------
__global__ __launch_bounds__(256) void fc_kernel(
    const float* __restrict__ pooled, const float* __restrict__ Wfc,
    const float* __restrict__ bfc, float* __restrict__ out)
{
    __shared__ float Wl[DIM * OUTD];   // 16 KB
    for (int i = threadIdx.x; i < DIM * OUTD; i += 256) Wl[i] = Wfc[i];
    __syncthreads();
    int t = blockIdx.x * 256 + threadIdx.x;
    if (t >= N_GRAPHS * OUTD) return;
    int g = t >> 7;
    int o = t & (OUTD - 1);
    float acc = bfc[o];
    const float* pr = pooled + (long)g * DIM;
#pragma unroll
    for (int k = 0; k < DIM; ++k) acc += pr[k] * Wl[k * OUTD + o];
    out[t] = fmaxf(acc, 0.f);
}

extern "C" void kernel_launch(void* const* d_in, const int* in_sizes, int n_in,
                              void* d_out, int out_size, void* d_ws, size_t ws_size,
                              hipStream_t stream) {
    const float* x      = (const float*)d_in[0];
    const int*   ei     = (const int*)  d_in[1];
    const int*   batch  = (const int*)  d_in[2];
    const float* W1_0   = (const float*)d_in[3];
    const float* W1_rest= (const float*)d_in[4];
    const float* b1     = (const float*)d_in[5];
    const float* W2     = (const float*)d_in[6];
    const float* b2     = (const float*)d_in[7];
    const float* gamma  = (const float*)d_in[8];
    const float* beta   = (const float*)d_in[9];
    const float* Wfc    = (const float*)d_in[10];
    const float* bfc    = (const float*)d_in[11];
    float* out = (float*)d_out;

    char* ws = (char*)d_ws;
    const size_t nf = (size_t)N_NODES * DIM;                   // 3.2M words
    float* y0     = (float*)ws;          // overlaid with bdata (3.2M words)
    int*   bdata  = (int*)y0;            // NB*NSUB*SUBCAP = 3,200,000 ints
    float* zA     = y0 + nf;
    float* zB     = zA + nf;
    float* pooled = zB + nf;                                   // 65536
    float* partial= pooled + (size_t)N_GRAPHS * DIM;           // 5*49*64
    float* ss     = partial + (size_t)NLAYERS * NSLOTS2 * 2 * DIM;  // 5*64
    float* W1p    = ss + NLAYERS * 2 * DIM;                    // 5*1024
    float* cvec   = W1p + NLAYERS * DIM * DIM;                 // 5*32
    int*   counts = (int*)(cvec + NLAYERS * DIM);
    int*   row_ptr= counts + N_NODES;                          // 100001
    int*   blockSums = row_ptr + (N_NODES + 1);                // 128
    int*   bcnt   = blockSums + 128;                           // NB*NSUB = 25000
    int*   edge_src = bcnt + NB * NSUB;                        // 1.6M

    // zero pooled + all partials (contiguous); zero bcnt
    hipMemsetAsync(pooled, 0,
        ((size_t)N_GRAPHS * DIM + (size_t)NLAYERS * NSLOTS2 * 2 * DIM) *
        sizeof(float), stream);
    hipMemsetAsync(bcnt, 0, (size_t)NB * NSUB * sizeof(int), stream);

    const int edgeBlocks = (N_EDGES + 255) / 256;
    const int grpBlocks = (N_NODES * 8) / 256;                 // 3125
    const int nsb = (N_NODES + SCAN_BLK - 1) / SCAN_BLK;       // 98

    // CSR build (bucketed, XCD-sharded tails)
    bfill_kernel<<<edgeBlocks, 256, 0, stream>>>(ei, bcnt, bdata);
    pcount_kernel<<<NB, 256, 0, stream>>>(bcnt, bdata, counts);
    scan_a_kernel<<<nsb, 256, 0, stream>>>(counts, blockSums);
    scan_b_kernel<<<1, 128, 0, stream>>>(blockSums, nsb);
    scan_c_kernel<<<nsb, 256, 0, stream>>>(counts, blockSums, row_ptr);
    cfill_kernel<<<NB, 256, 0, stream>>>(bcnt, bdata, row_ptr, edge_src);

    // layer 0 input projection (x is only used here)
    gemm1_kernel<<<grpBlocks, 256, 0, stream>>>(x, W1_0, y0);

    // layer 0: gather y0, no matmul fold
    layer_kernel<false><<<NB, 256, 0, stream>>>(
        row_ptr, edge_src, y0, nullptr, nullptr,
        b1, W2, b2, zA, partial);
    finalize_kernel<<<1, 256, 0, stream>>>(
        partial, gamma, beta, ss,
        W1_rest, W1p + DIM * DIM, cvec + DIM);

    // layers 1..4: fused affine+W1 fold
    const float* zi = zA;
    float* zo = zB;
    for (int i = 1; i < NLAYERS; ++i) {
        layer_kernel<true><<<NB, 256, 0, stream>>>(
            row_ptr, edge_src, zi,
            W1p + (size_t)i * DIM * DIM, cvec + (size_t)i * DIM,
            b1 + i * DIM, W2 + (size_t)i * DIM * DIM, b2 + i * DIM,
            zo, partial + (size_t)i * NSLOTS2 * 2 * DIM);
        const float* W1next = (i + 1 < NLAYERS) ? (W1_rest + (size_t)i * DIM * DIM)
                                                : nullptr;
        finalize_kernel<<<1, 256, 0, stream>>>(
            partial + (size_t)i * NSLOTS2 * 2 * DIM,
            gamma + i * DIM, beta + i * DIM, ss + i * 2 * DIM,
            W1next, W1p + (size_t)(i + 1) * DIM * DIM,
            cvec + (size_t)(i + 1) * DIM);
        const float* tmp = zi; zi = zo; zo = (float*)tmp;
    }

    // zi now points at the final layer's output (zA after 5 layers)
    pool_kernel<<<N_NODES / 32, 256, 0, stream>>>(
        zi, batch, ss + (NLAYERS - 1) * 2 * DIM, pooled);
    fc_kernel<<<(N_GRAPHS * OUTD) / 256, 256, 0, stream>>>(pooled, Wfc, bfc, out);
}

// Round 8
// 371.401 us; speedup vs baseline: 2.0805x; 1.2190x over previous
//
#include <hip/hip_runtime.h>
#include <hip/hip_fp16.h>

#define N_NODES 100000
#define N_EDGES 1600000
#define N_GRAPHS 2048
#define NFEAT 78
#define DIM 32
#define NLAYERS 5
#define OUTD 128
#define BN_EPS 1e-5f
#define NB 3125        // buckets = N_NODES/32
#define NPB 32         // nodes per bucket
#define NSUB 8         // sub-tails per bucket (sharded by blockIdx&7 ~ XCD)
#define SUBCAP 128     // per-sub capacity (mean 64, ~8 sigma)
#define ESTRIDE 768    // edge slab per bucket (mean 512, ~11 sigma)
#define NSLOTS2 ((NB + 63) / 64)   // 49 partial-stats slots

// fp16 helpers: unsigned holds 2 halfs
__device__ __forceinline__ float2 up2(unsigned u) {
    __half2 h = *reinterpret_cast<__half2*>(&u);
    return __half22float2(h);
}
__device__ __forceinline__ unsigned pk2(float a, float b) {
    __half2 h = __floats2half2_rn(a, b);
    return *reinterpret_cast<unsigned*>(&h);
}

// ---------- bucket fill: XCD-sharded tails ----------
__global__ __launch_bounds__(256) void bfill_kernel(
    const int* __restrict__ ei, int* __restrict__ bcnt, int* __restrict__ bdata)
{
    int e = blockIdx.x * 256 + threadIdx.x;
    if (e >= N_EDGES) return;
    int sub = blockIdx.x & (NSUB - 1);
    int src = ei[e];
    int dst = ei[N_EDGES + e];
    int b = dst >> 5;
    int pos = atomicAdd(&bcnt[b * NSUB + sub], 1);
    if (pos < SUBCAP)
        bdata[b * (NSUB * SUBCAP) + sub * SUBCAP + pos] = src | ((dst & 31) << 20);
}

// ---- single-pass bucket-local CSR: count, scan, sort, emit offs ----
__global__ __launch_bounds__(256) void cfill2_kernel(
    const int* __restrict__ bcnt, const int* __restrict__ bdata,
    int* __restrict__ edge_src, int* __restrict__ offs)
{
    __shared__ int sorted[NSUB * SUBCAP];   // 4 KB
    __shared__ int cnt[NPB], cur[NPB], off[NPB + 1];
    __shared__ int ns[NSUB];
    int b = blockIdx.x, tid = threadIdx.x;
    if (tid < NPB) cnt[tid] = 0;
    if (tid < NSUB) {
        int v = bcnt[b * NSUB + tid];
        ns[tid] = v < SUBCAP ? v : SUBCAP;
    }
    __syncthreads();
    int vals[4];
#pragma unroll
    for (int k = 0; k < 4; ++k) {
        int i = tid + k * 256;
        int sub = i >> 7, pos = i & (SUBCAP - 1);
        int d = -1;
        if (pos < ns[sub]) {
            d = bdata[b * (NSUB * SUBCAP) + i];
            atomicAdd(&cnt[d >> 20], 1);
        }
        vals[k] = d;
    }
    __syncthreads();
    if (tid == 0) {
        int run = 0;
#pragma unroll
        for (int i = 0; i < NPB; ++i) { off[i] = run; cur[i] = run; run += cnt[i]; }
        off[NPB] = run;
    }
    __syncthreads();
#pragma unroll
    for (int k = 0; k < 4; ++k) {
        int d = vals[k];
        if (d >= 0) {
            int pos = atomicAdd(&cur[d >> 20], 1);
            sorted[pos] = d & 0xFFFFF;
        }
    }
    __syncthreads();
    int total = off[NPB];
    for (int i = tid; i < total; i += 256)
        edge_src[(long)b * ESTRIDE + i] = sorted[i];
    if (tid <= NPB) offs[b * (NPB + 1) + tid] = off[tid];
}

// ---------- GEMM1 layer0 (8 threads/row): y0 = x @ W1_0 -> fp16 ----------
__global__ __launch_bounds__(256) void gemm1_kernel(
    const float* __restrict__ h, const float* __restrict__ W,
    unsigned short* __restrict__ y)
{
    __shared__ float Wl[NFEAT * DIM];   // 9.75 KB
    for (int i = threadIdx.x; i < NFEAT * DIM; i += 256) Wl[i] = W[i];
    __syncthreads();

    int t = blockIdx.x * 256 + threadIdx.x;
    int row = t >> 3;
    int c0 = (t & 7) * 4;

    float a0 = 0.f, a1 = 0.f, a2 = 0.f, a3 = 0.f;
    const float* hr = h + (long)row * NFEAT;
    for (int k = 0; k < NFEAT; ++k) {
        float xv = hr[k];
        a0 = fmaf(xv, Wl[k * DIM + c0 + 0], a0);
        a1 = fmaf(xv, Wl[k * DIM + c0 + 1], a1);
        a2 = fmaf(xv, Wl[k * DIM + c0 + 2], a2);
        a3 = fmaf(xv, Wl[k * DIM + c0 + 3], a3);
    }
    ((uint2*)y)[(long)row * 8 + (t & 7)] = make_uint2(pk2(a0, a1), pk2(a2, a3));
}

// ---- fused layer: fp16 gather -> [@W1'+(deg+1)c+b1] -> relu -> @W2+b2
//      -> relu -> fp16 zout + BN partial stats.  One block = 32 nodes. ----
template<bool MM>
__global__ __launch_bounds__(256) void layer_kernel(
    const int* __restrict__ offs, const int* __restrict__ edge_src,
    const unsigned short* __restrict__ zin, const float* __restrict__ W1p,
    const float* __restrict__ cvec, const float* __restrict__ b1v,
    const float* __restrict__ W2, const float* __restrict__ b2v,
    unsigned short* __restrict__ zout, float* __restrict__ partial)
{
    __shared__ float W1l[DIM * DIM];       // 4 KB (used iff MM)
    __shared__ float W2l[DIM * DIM];       // 4 KB
    __shared__ float zs[NPB][36];          // 4.5 KB
    __shared__ float srow[NPB][36];        // 4.5 KB
    __shared__ float b1l[DIM], b2l[DIM], cl[DIM];
    __shared__ float psum[DIM], psq[DIM];

    int tid = threadIdx.x;
    if (MM) for (int i = tid; i < DIM * DIM; i += 256) W1l[i] = W1p[i];
    for (int i = tid; i < DIM * DIM; i += 256) W2l[i] = W2[i];
    if (tid < DIM) {
        b1l[tid] = b1v[tid]; b2l[tid] = b2v[tid];
        cl[tid] = MM ? cvec[tid] : 0.f;
        psum[tid] = 0.f; psq[tid] = 0.f;
    }
    __syncthreads();

    int ln = tid >> 3, p = tid & 7;
    int c0 = p * 4;
    long node = (long)blockIdx.x * NPB + ln;
    int obase = blockIdx.x * (NPB + 1);
    int beg = offs[obase + ln], end = offs[obase + ln + 1];
    int deg = end - beg;
    const int* es = edge_src + (long)blockIdx.x * ESTRIDE;
    const uint2* zb = (const uint2*)zin;

    // phase 1: gather (self + in-neighbors), unroll x4 for MLP of loads
    uint2 sv = zb[node * 8 + p];
    float2 s01 = up2(sv.x), s23 = up2(sv.y);
    float a0 = s01.x, a1 = s01.y, a2 = s23.x, a3 = s23.y;
    int e = beg;
    for (; e + 4 <= end; e += 4) {
        int i0 = es[e], i1 = es[e + 1], i2 = es[e + 2], i3 = es[e + 3];
        uint2 v0 = zb[(long)i0 * 8 + p];
        uint2 v1 = zb[(long)i1 * 8 + p];
        uint2 v2 = zb[(long)i2 * 8 + p];
        uint2 v3 = zb[(long)i3 * 8 + p];
        float2 f;
        f = up2(v0.x); a0 += f.x; a1 += f.y;  f = up2(v0.y); a2 += f.x; a3 += f.y;
        f = up2(v1.x); a0 += f.x; a1 += f.y;  f = up2(v1.y); a2 += f.x; a3 += f.y;
        f = up2(v2.x); a0 += f.x; a1 += f.y;  f = up2(v2.y); a2 += f.x; a3 += f.y;
        f = up2(v3.x); a0 += f.x; a1 += f.y;  f = up2(v3.y); a2 += f.x; a3 += f.y;
    }
    for (; e < end; ++e) {
        int s = es[e];
        uint2 v = zb[(long)s * 8 + p];
        float2 f;
        f = up2(v.x); a0 += f.x; a1 += f.y;
        f = up2(v.y); a2 += f.x; a3 += f.y;
    }
    *(float4*)&zs[ln][c0] = make_float4(a0, a1, a2, a3);
    __syncthreads();

    // phase 2: s = zsum@W1' + (deg+1)*c + b1  (or zsum + b1), relu
    float sv4[4];
    if (MM) {
        sv4[0] = sv4[1] = sv4[2] = sv4[3] = 0.f;
#pragma unroll
        for (int k = 0; k < DIM; ++k) {
            float zk = zs[ln][k];
            sv4[0] = fmaf(zk, W1l[k * DIM + c0 + 0], sv4[0]);
            sv4[1] = fmaf(zk, W1l[k * DIM + c0 + 1], sv4[1]);
            sv4[2] = fmaf(zk, W1l[k * DIM + c0 + 2], sv4[2]);
            sv4[3] = fmaf(zk, W1l[k * DIM + c0 + 3], sv4[3]);
        }
        float dp1 = (float)(deg + 1);
#pragma unroll
        for (int j = 0; j < 4; ++j)
            sv4[j] = fmaf(dp1, cl[c0 + j], sv4[j]) + b1l[c0 + j];
    } else {
        sv4[0] = a0 + b1l[c0 + 0]; sv4[1] = a1 + b1l[c0 + 1];
        sv4[2] = a2 + b1l[c0 + 2]; sv4[3] = a3 + b1l[c0 + 3];
    }
    float4 srw = make_float4(fmaxf(sv4[0], 0.f), fmaxf(sv4[1], 0.f),
                             fmaxf(sv4[2], 0.f), fmaxf(sv4[3], 0.f));
    *(float4*)&srow[ln][c0] = srw;
    __syncthreads();

    // phase 3: z = relu(srow@W2 + b2), fp16 write + stats
    float zv[4] = { b2l[c0 + 0], b2l[c0 + 1], b2l[c0 + 2], b2l[c0 + 3] };
#pragma unroll
    for (int k = 0; k < DIM; ++k) {
        float sk = srow[ln][k];
        zv[0] = fmaf(sk, W2l[k * DIM + c0 + 0], zv[0]);
        zv[1] = fmaf(sk, W2l[k * DIM + c0 + 1], zv[1]);
        zv[2] = fmaf(sk, W2l[k * DIM + c0 + 2], zv[2]);
        zv[3] = fmaf(sk, W2l[k * DIM + c0 + 3], zv[3]);
    }
#pragma unroll
    for (int j = 0; j < 4; ++j) zv[j] = fmaxf(zv[j], 0.f);
    ((uint2*)zout)[node * 8 + p] = make_uint2(pk2(zv[0], zv[1]), pk2(zv[2], zv[3]));

    float sq[4];
#pragma unroll
    for (int j = 0; j < 4; ++j) sq[j] = zv[j] * zv[j];
#pragma unroll
    for (int off = 8; off < 64; off <<= 1) {
#pragma unroll
        for (int j = 0; j < 4; ++j) {
            zv[j] += __shfl_xor(zv[j], off, 64);
            sq[j] += __shfl_xor(sq[j], off, 64);
        }
    }
    if ((tid & 63) < 8) {
#pragma unroll
        for (int j = 0; j < 4; ++j) {
            atomicAdd(&psum[c0 + j], zv[j]);
            atomicAdd(&psq[c0 + j], sq[j]);
        }
    }
    __syncthreads();
    if (tid < 2 * DIM) {
        float v = (tid < DIM) ? psum[tid] : psq[tid - DIM];
        atomicAdd(&partial[(long)(blockIdx.x >> 6) * 2 * DIM + tid], v);
    }
}

// ------ finalize: stats -> scale/shift; fold next layer's W1' and c ------
__global__ __launch_bounds__(256) void finalize_kernel(
    const float* __restrict__ partial,
    const float* __restrict__ gamma, const float* __restrict__ beta,
    float* __restrict__ ss, const float* W1next,
    float* __restrict__ W1p, float* __restrict__ cvec)
{
    __shared__ float red[256];
    __shared__ float sscl[DIM], sshl[DIM];
    int t = threadIdx.x;
    int c = t & 63;
    int chunk = t >> 6;
    float a = 0.f;
    for (int p = chunk; p < NSLOTS2; p += 4) a += partial[(long)p * 64 + c];
    red[t] = a; __syncthreads();
    if (t < 64) red[t] = red[t] + red[t + 64] + red[t + 128] + red[t + 192];
    __syncthreads();
    if (t < DIM) {
        const float invN = 1.0f / (float)N_NODES;
        float S = red[t], Q = red[t + DIM];
        float mu = S * invN;
        float var = Q * invN - mu * mu;
        float scale = gamma[t] * rsqrtf(var + BN_EPS);
        float shift = beta[t] - mu * scale;
        ss[t] = scale; ss[DIM + t] = shift;
        sscl[t] = scale; sshl[t] = shift;
    }
    __syncthreads();
    if (W1next) {
        for (int i = t; i < DIM * DIM; i += 256)
            W1p[i] = sscl[i >> 5] * W1next[i];
        if (t < DIM) {
            float cv = 0.f;
            for (int k = 0; k < DIM; ++k)
                cv += sshl[k] * W1next[k * DIM + t];
            cvec[t] = cv;
        }
    }
}

// ------- pool: pooled[g] += affine(zfp16[node]); sorted-batch LDS dedup -------
__global__ __launch_bounds__(256) void pool_kernel(
    const unsigned short* __restrict__ z, const int* __restrict__ batch,
    const float* __restrict__ ss, float* __restrict__ pooled)
{
    __shared__ float acc[32][32];
    __shared__ int slot[32];
    __shared__ int segg[32];
    __shared__ int nsegS;
    __shared__ float scl[DIM], shl[DIM];
    int tid = threadIdx.x;
    for (int i = tid; i < 1024; i += 256) ((float*)acc)[i] = 0.f;
    if (tid < DIM) { scl[tid] = ss[tid]; shl[tid] = ss[DIM + tid]; }
    int nodeBase = blockIdx.x * 32;
    if (tid < 32) {
        int nd = nodeBase + tid;
        int gv = batch[nd];
        int flag = (tid == 0) ? 1 : (gv != batch[nd - 1]);
        unsigned long long m = __ballot(flag);
        int s = __popcll(m & ((2ull << tid) - 1ull)) - 1;
        slot[tid] = s;
        if (flag) segg[s] = gv;
        if (tid == 0) nsegS = __popcll(m);
    }
    __syncthreads();

    int ln = tid >> 3;
    int p = tid & 7;
    long node = nodeBase + ln;
    uint2 u = ((const uint2*)z)[node * 8 + p];
    int c = p * 4;
    float2 f01 = up2(u.x), f23 = up2(u.y);
    float vx = fmaf(f01.x, scl[c+0], shl[c+0]);
    float vy = fmaf(f01.y, scl[c+1], shl[c+1]);
    float vz = fmaf(f23.x, scl[c+2], shl[c+2]);
    float vw = fmaf(f23.y, scl[c+3], shl[c+3]);
    int s = slot[ln];
    atomicAdd(&acc[s][c+0], vx);
    atomicAdd(&acc[s][c+1], vy);
    atomicAdd(&acc[s][c+2], vz);
    atomicAdd(&acc[s][c+3], vw);
    __syncthreads();

    int total = nsegS * 32;
    for (int i = tid; i < total; i += 256) {
        int r = i >> 5, dd = i & 31;
        float val = acc[r][dd];
        if (val != 0.f) atomicAdd(&pooled[(long)segg[r] * DIM + dd], val);
    }
}

// ---------------- final FC + ReLU ----------------
__global__ __launch_bounds__(256) void fc_kernel(
    const float* __restrict__ pooled, const float* __restrict__ Wfc,
    const float* __restrict__ bfc, float* __restrict__ out)
{
    __shared__ float Wl[DIM * OUTD];   // 16 KB
    for (int i = threadIdx.x; i < DIM * OUTD; i += 256) Wl[i] = Wfc[i];
    __syncthreads();
    int t = blockIdx.x * 256 + threadIdx.x;
    if (t >= N_GRAPHS * OUTD) return;
    int g = t >> 7;
    int o = t & (OUTD - 1);
    float acc = bfc[o];
    const float* pr = pooled + (long)g * DIM;
#pragma unroll
    for (int k = 0; k < DIM; ++k) acc += pr[k] * Wl[k * OUTD + o];
    out[t] = fmaxf(acc, 0.f);
}

extern "C" void kernel_launch(void* const* d_in, const int* in_sizes, int n_in,
                              void* d_out, int out_size, void* d_ws, size_t ws_size,
                              hipStream_t stream) {
    const float* x      = (const float*)d_in[0];
    const int*   ei     = (const int*)  d_in[1];
    const int*   batch  = (const int*)  d_in[2];
    const float* W1_0   = (const float*)d_in[3];
    const float* W1_rest= (const float*)d_in[4];
    const float* b1     = (const float*)d_in[5];
    const float* W2     = (const float*)d_in[6];
    const float* b2     = (const float*)d_in[7];
    const float* gamma  = (const float*)d_in[8];
    const float* beta   = (const float*)d_in[9];
    const float* Wfc    = (const float*)d_in[10];
    const float* bfc    = (const float*)d_in[11];
    float* out = (float*)d_out;

    char* ws = (char*)d_ws;
    const size_t nf = (size_t)N_NODES * DIM;                   // 3.2M elems
    // bdata (3.2M ints, 12.8MB) overlays zfpA+zfpB (each 3.2M ushorts, 6.4MB)
    int*   bdata  = (int*)ws;
    unsigned short* zfpA = (unsigned short*)ws;
    unsigned short* zfpB = zfpA + nf;
    float* pooled = (float*)(ws + (size_t)NB * NSUB * SUBCAP * sizeof(int));
    float* partial= pooled + (size_t)N_GRAPHS * DIM;           // 5*49*64
    float* ss     = partial + (size_t)NLAYERS * NSLOTS2 * 2 * DIM;  // 5*64
    float* W1p    = ss + NLAYERS * 2 * DIM;                    // 5*1024
    float* cvec   = W1p + NLAYERS * DIM * DIM;                 // 5*32
    int*   offs   = (int*)(cvec + NLAYERS * DIM);              // NB*33
    int*   bcnt   = offs + NB * (NPB + 1);                     // NB*NSUB = 25000
    int*   edge_src = bcnt + NB * NSUB;                        // NB*ESTRIDE = 2.4M

    // zero pooled + all partials (contiguous); zero bcnt
    hipMemsetAsync(pooled, 0,
        ((size_t)N_GRAPHS * DIM + (size_t)NLAYERS * NSLOTS2 * 2 * DIM) *
        sizeof(float), stream);
    hipMemsetAsync(bcnt, 0, (size_t)NB * NSUB * sizeof(int), stream);

    const int edgeBlocks = (N_EDGES + 255) / 256;
    const int grpBlocks = (N_NODES * 8) / 256;                 // 3125

    // CSR build: bucketed fill + single-pass bucket-local sort
    bfill_kernel<<<edgeBlocks, 256, 0, stream>>>(ei, bcnt, bdata);
    cfill2_kernel<<<NB, 256, 0, stream>>>(bcnt, bdata, edge_src, offs);

    // layer 0 input projection -> fp16 (overlays bdata; stream-ordered after cfill2)
    gemm1_kernel<<<grpBlocks, 256, 0, stream>>>(x, W1_0, zfpA);

    // layer 0: gather y0, no matmul fold
    layer_kernel<false><<<NB, 256, 0, stream>>>(
        offs, edge_src, zfpA, nullptr, nullptr,
        b1, W2, b2, zfpB, partial);
    finalize_kernel<<<1, 256, 0, stream>>>(
        partial, gamma, beta, ss,
        W1_rest, W1p + DIM * DIM, cvec + DIM);

    // layers 1..4: fused affine+W1 fold
    const unsigned short* zi = zfpB;
    unsigned short* zo = zfpA;
    for (int i = 1; i < NLAYERS; ++i) {
        layer_kernel<true><<<NB, 256, 0, stream>>>(
            offs, edge_src, zi,
            W1p + (size_t)i * DIM * DIM, cvec + (size_t)i * DIM,
            b1 + i * DIM, W2 + (size_t)i * DIM * DIM, b2 + i * DIM,
            zo, partial + (size_t)i * NSLOTS2 * 2 * DIM);
        const float* W1next = (i + 1 < NLAYERS) ? (W1_rest + (size_t)i * DIM * DIM)
                                                : nullptr;
        finalize_kernel<<<1, 256, 0, stream>>>(
            partial + (size_t)i * NSLOTS2 * 2 * DIM,
            gamma + i * DIM, beta + i * DIM, ss + i * 2 * DIM,
            W1next, W1p + (size_t)(i + 1) * DIM * DIM,
            cvec + (size_t)(i + 1) * DIM);
        const unsigned short* tmp = zi; zi = zo; zo = (unsigned short*)tmp;
    }

    // zi points at the final layer's output
    pool_kernel<<<N_NODES / 32, 256, 0, stream>>>(
        zi, batch, ss + (NLAYERS - 1) * 2 * DIM, pooled);
    fc_kernel<<<(N_GRAPHS * OUTD) / 256, 256, 0, stream>>>(pooled, Wfc, bfc, out);
}

// Round 9
// 311.051 us; speedup vs baseline: 2.4841x; 1.1940x over previous
//
#include <hip/hip_runtime.h>
#include <hip/hip_fp16.h>

#define N_NODES 100000
#define N_EDGES 1600000
#define N_GRAPHS 2048
#define NFEAT 78
#define DIM 32
#define NLAYERS 5
#define OUTD 128
#define BN_EPS 1e-5f
#define NPB 32                       // nodes per layer-block
#define NBUK 391                     // coarse buckets (256 nodes each)
#define BNODES 256                   // nodes per bucket
#define STRIDE 4608                  // slab per bucket (mean 4092, +8 sigma)
#define EPB 4096                     // edges per bfill2 block
#define NSLOTS2 ((N_NODES / NPB + 63) / 64)   // 49 partial-stats slots

// fp16 helpers: unsigned holds 2 halfs
__device__ __forceinline__ float2 up2(unsigned u) {
    __half2 h = *reinterpret_cast<__half2*>(&u);
    return __half22float2(h);
}
__device__ __forceinline__ unsigned pk2(float a, float b) {
    __half2 h = __floats2half2_rn(a, b);
    return *reinterpret_cast<unsigned*>(&h);
}

// ---- bfill2: LDS pre-sort 4096 edges/block, one global atomic per
//      (block,bucket), write word = src | local<<17 into bucket slabs ----
__global__ __launch_bounds__(256) void bfill2_kernel(
    const int* __restrict__ ei, int* __restrict__ bcnt, int* __restrict__ bdata)
{
    __shared__ int cur[NBUK];
    __shared__ int gbl[NBUK];
    int tid = threadIdx.x;
    int base = blockIdx.x * EPB;

    for (int i = tid; i < NBUK; i += 256) cur[i] = 0;
    __syncthreads();

    int ew[16];   // src | local<<17
    int eb[16];   // bucket or -1
    const int4* s4 = (const int4*)ei;
    const int4* d4 = (const int4*)(ei + N_EDGES);
#pragma unroll
    for (int c = 0; c < 4; ++c) {
        int eidx = base + c * 1024 + tid * 4;
        if (eidx < N_EDGES) {
            int4 sv = s4[eidx >> 2];
            int4 dv = d4[eidx >> 2];
            ew[c*4+0] = sv.x | ((dv.x & 255) << 17); eb[c*4+0] = dv.x >> 8;
            ew[c*4+1] = sv.y | ((dv.y & 255) << 17); eb[c*4+1] = dv.y >> 8;
            ew[c*4+2] = sv.z | ((dv.z & 255) << 17); eb[c*4+2] = dv.z >> 8;
            ew[c*4+3] = sv.w | ((dv.w & 255) << 17); eb[c*4+3] = dv.w >> 8;
        } else {
            eb[c*4+0] = eb[c*4+1] = eb[c*4+2] = eb[c*4+3] = -1;
            ew[c*4+0] = ew[c*4+1] = ew[c*4+2] = ew[c*4+3] = 0;
        }
    }

    int slot[16];
#pragma unroll
    for (int k = 0; k < 16; ++k)
        slot[k] = (eb[k] >= 0) ? atomicAdd(&cur[eb[k]], 1) : 0;
    __syncthreads();

    for (int b = tid; b < NBUK; b += 256) {
        int c = cur[b];
        gbl[b] = (c > 0) ? atomicAdd(&bcnt[b], c) : 0;
    }
    __syncthreads();

#pragma unroll
    for (int k = 0; k < 16; ++k) {
        int b = eb[k];
        if (b >= 0) {
            int pos = gbl[b] + slot[k];
            if (pos < STRIDE) bdata[b * STRIDE + pos] = ew[k];
        }
    }
}

// ---- bscan: exclusive scan of 391 bucket totals -> bbase[0..391] ----
__global__ __launch_bounds__(512) void bscan_kernel(
    const int* __restrict__ bcnt, int* __restrict__ bbase)
{
    __shared__ int sd[512];
    int t = threadIdx.x;
    int v = (t < NBUK) ? min(bcnt[t], STRIDE) : 0;
    sd[t] = v; __syncthreads();
    for (int off = 1; off < 512; off <<= 1) {
        int a = (t >= off) ? sd[t - off] : 0;
        __syncthreads();
        sd[t] += a;
        __syncthreads();
    }
    if (t < NBUK) bbase[t + 1] = sd[t];
    if (t == 0) bbase[0] = 0;
}

// ---- cfill2: per-bucket LDS counting sort -> flat CSR (edge_src, offs) ----
__global__ __launch_bounds__(256) void cfill2_kernel(
    const int* __restrict__ bcnt, const int* __restrict__ bbase,
    const int* __restrict__ bdata, int* __restrict__ edge_src,
    int* __restrict__ offs)
{
    __shared__ int sorted[STRIDE];          // 18.4 KB
    __shared__ int cnt[BNODES], off[BNODES], cur[BNODES];
    int b = blockIdx.x, tid = threadIdx.x;
    int n = min(bcnt[b], STRIDE);
    int gb = bbase[b];
    const int* slab = bdata + (long)b * STRIDE;

    if (tid < BNODES) cnt[tid] = 0;
    __syncthreads();
    for (int i = tid; i < n; i += 256)
        atomicAdd(&cnt[slab[i] >> 17], 1);
    __syncthreads();
    // inclusive scan of cnt -> off (exclusive)
    int t = tid;
    if (t < BNODES) off[t] = cnt[t];
    __syncthreads();
    for (int o = 1; o < BNODES; o <<= 1) {
        int a = (t >= o && t < BNODES) ? off[t - o] : 0;
        __syncthreads();
        if (t < BNODES) off[t] += a;
        __syncthreads();
    }
    if (t < BNODES) {
        int excl = off[t] - cnt[t];
        off[t] = excl;
        cur[t] = excl;
        int node = b * BNODES + t;
        if (node <= N_NODES) offs[node] = gb + excl;
    }
    __syncthreads();
    for (int i = tid; i < n; i += 256) {
        int w = slab[i];
        int pos = atomicAdd(&cur[w >> 17], 1);
        sorted[pos] = w & 0x1FFFF;
    }
    __syncthreads();
    for (int i = tid; i < n; i += 256)
        edge_src[gb + i] = sorted[i];
    // offs[N_NODES] handled by bucket containing node 100000 (b=390,t=160)
}

// ---------- GEMM1 layer0 (8 threads/row): y0 = x @ W1_0 -> fp16 ----------
__global__ __launch_bounds__(256) void gemm1_kernel(
    const float* __restrict__ h, const float* __restrict__ W,
    unsigned short* __restrict__ y)
{
    __shared__ float Wl[NFEAT * DIM];   // 9.75 KB
    for (int i = threadIdx.x; i < NFEAT * DIM; i += 256) Wl[i] = W[i];
    __syncthreads();

    int t = blockIdx.x * 256 + threadIdx.x;
    int row = t >> 3;
    int c0 = (t & 7) * 4;

    float a0 = 0.f, a1 = 0.f, a2 = 0.f, a3 = 0.f;
    const float* hr = h + (long)row * NFEAT;
    for (int k = 0; k < NFEAT; ++k) {
        float xv = hr[k];
        a0 = fmaf(xv, Wl[k * DIM + c0 + 0], a0);
        a1 = fmaf(xv, Wl[k * DIM + c0 + 1], a1);
        a2 = fmaf(xv, Wl[k * DIM + c0 + 2], a2);
        a3 = fmaf(xv, Wl[k * DIM + c0 + 3], a3);
    }
    ((uint2*)y)[(long)row * 8 + (t & 7)] = make_uint2(pk2(a0, a1), pk2(a2, a3));
}

// ---- fused layer (flat CSR): fp16 gather -> [@W1'+(deg+1)c+b1] -> relu
//      -> @W2+b2 -> relu -> fp16 zout + BN partials. Block = 32 nodes. ----
template<bool MM>
__global__ __launch_bounds__(256) void layer_kernel(
    const int* __restrict__ offs, const int* __restrict__ edge_src,
    const unsigned short* __restrict__ zin, const float* __restrict__ W1p,
    const float* __restrict__ cvec, const float* __restrict__ b1v,
    const float* __restrict__ W2, const float* __restrict__ b2v,
    unsigned short* __restrict__ zout, float* __restrict__ partial)
{
    __shared__ float W1l[DIM * DIM];
    __shared__ float W2l[DIM * DIM];
    __shared__ float zs[NPB][36];
    __shared__ float srow[NPB][36];
    __shared__ float b1l[DIM], b2l[DIM], cl[DIM];
    __shared__ float psum[DIM], psq[DIM];

    int tid = threadIdx.x;
    if (MM) for (int i = tid; i < DIM * DIM; i += 256) W1l[i] = W1p[i];
    for (int i = tid; i < DIM * DIM; i += 256) W2l[i] = W2[i];
    if (tid < DIM) {
        b1l[tid] = b1v[tid]; b2l[tid] = b2v[tid];
        cl[tid] = MM ? cvec[tid] : 0.f;
        psum[tid] = 0.f; psq[tid] = 0.f;
    }
    __syncthreads();

    int ln = tid >> 3, p = tid & 7;
    int c0 = p * 4;
    long node = (long)blockIdx.x * NPB + ln;
    int beg = offs[node], end = offs[node + 1];
    int deg = end - beg;
    const uint2* zb = (const uint2*)zin;

    // phase 1: gather (self + in-neighbors), unroll x8
    uint2 sv = zb[node * 8 + p];
    float2 s01 = up2(sv.x), s23 = up2(sv.y);
    float a0 = s01.x, a1 = s01.y, a2 = s23.x, a3 = s23.y;
    int e = beg;
    for (; e + 8 <= end; e += 8) {
        uint2 v0 = zb[(long)edge_src[e + 0] * 8 + p];
        uint2 v1 = zb[(long)edge_src[e + 1] * 8 + p];
        uint2 v2 = zb[(long)edge_src[e + 2] * 8 + p];
        uint2 v3 = zb[(long)edge_src[e + 3] * 8 + p];
        uint2 v4 = zb[(long)edge_src[e + 4] * 8 + p];
        uint2 v5 = zb[(long)edge_src[e + 5] * 8 + p];
        uint2 v6 = zb[(long)edge_src[e + 6] * 8 + p];
        uint2 v7 = zb[(long)edge_src[e + 7] * 8 + p];
        float2 f;
        f = up2(v0.x); a0 += f.x; a1 += f.y;  f = up2(v0.y); a2 += f.x; a3 += f.y;
        f = up2(v1.x); a0 += f.x; a1 += f.y;  f = up2(v1.y); a2 += f.x; a3 += f.y;
        f = up2(v2.x); a0 += f.x; a1 += f.y;  f = up2(v2.y); a2 += f.x; a3 += f.y;
        f = up2(v3.x); a0 += f.x; a1 += f.y;  f = up2(v3.y); a2 += f.x; a3 += f.y;
        f = up2(v4.x); a0 += f.x; a1 += f.y;  f = up2(v4.y); a2 += f.x; a3 += f.y;
        f = up2(v5.x); a0 += f.x; a1 += f.y;  f = up2(v5.y); a2 += f.x; a3 += f.y;
        f = up2(v6.x); a0 += f.x; a1 += f.y;  f = up2(v6.y); a2 += f.x; a3 += f.y;
        f = up2(v7.x); a0 += f.x; a1 += f.y;  f = up2(v7.y); a2 += f.x; a3 += f.y;
    }
    for (; e < end; ++e) {
        uint2 v = zb[(long)edge_src[e] * 8 + p];
        float2 f;
        f = up2(v.x); a0 += f.x; a1 += f.y;
        f = up2(v.y); a2 += f.x; a3 += f.y;
    }
    *(float4*)&zs[ln][c0] = make_float4(a0, a1, a2, a3);
    __syncthreads();

    // phase 2: s = zsum@W1' + (deg+1)*c + b1  (or zsum + b1), relu
    float sv4[4];
    if (MM) {
        sv4[0] = sv4[1] = sv4[2] = sv4[3] = 0.f;
#pragma unroll
        for (int k = 0; k < DIM; ++k) {
            float zk = zs[ln][k];
            sv4[0] = fmaf(zk, W1l[k * DIM + c0 + 0], sv4[0]);
            sv4[1] = fmaf(zk, W1l[k * DIM + c0 + 1], sv4[1]);
            sv4[2] = fmaf(zk, W1l[k * DIM + c0 + 2], sv4[2]);
            sv4[3] = fmaf(zk, W1l[k * DIM + c0 + 3], sv4[3]);
        }
        float dp1 = (float)(deg + 1);
#pragma unroll
        for (int j = 0; j < 4; ++j)
            sv4[j] = fmaf(dp1, cl[c0 + j], sv4[j]) + b1l[c0 + j];
    } else {
        sv4[0] = a0 + b1l[c0 + 0]; sv4[1] = a1 + b1l[c0 + 1];
        sv4[2] = a2 + b1l[c0 + 2]; sv4[3] = a3 + b1l[c0 + 3];
    }
    float4 srw = make_float4(fmaxf(sv4[0], 0.f), fmaxf(sv4[1], 0.f),
                             fmaxf(sv4[2], 0.f), fmaxf(sv4[3], 0.f));
    *(float4*)&srow[ln][c0] = srw;
    __syncthreads();

    // phase 3: z = relu(srow@W2 + b2), fp16 write + stats
    float zv[4] = { b2l[c0 + 0], b2l[c0 + 1], b2l[c0 + 2], b2l[c0 + 3] };
#pragma unroll
    for (int k = 0; k < DIM; ++k) {
        float sk = srow[ln][k];
        zv[0] = fmaf(sk, W2l[k * DIM + c0 + 0], zv[0]);
        zv[1] = fmaf(sk, W2l[k * DIM + c0 + 1], zv[1]);
        zv[2] = fmaf(sk, W2l[k * DIM + c0 + 2], zv[2]);
        zv[3] = fmaf(sk, W2l[k * DIM + c0 + 3], zv[3]);
    }
#pragma unroll
    for (int j = 0; j < 4; ++j) zv[j] = fmaxf(zv[j], 0.f);
    ((uint2*)zout)[node * 8 + p] = make_uint2(pk2(zv[0], zv[1]), pk2(zv[2], zv[3]));

    float sq[4];
#pragma unroll
    for (int j = 0; j < 4; ++j) sq[j] = zv[j] * zv[j];
#pragma unroll
    for (int off = 8; off < 64; off <<= 1) {
#pragma unroll
        for (int j = 0; j < 4; ++j) {
            zv[j] += __shfl_xor(zv[j], off, 64);
            sq[j] += __shfl_xor(sq[j], off, 64);
        }
    }
    if ((tid & 63) < 8) {
#pragma unroll
        for (int j = 0; j < 4; ++j) {
            atomicAdd(&psum[c0 + j], zv[j]);
            atomicAdd(&psq[c0 + j], sq[j]);
        }
    }
    __syncthreads();
    if (tid < 2 * DIM) {
        float v = (tid < DIM) ? psum[tid] : psq[tid - DIM];
        atomicAdd(&partial[(long)(blockIdx.x >> 6) * 2 * DIM + tid], v);
    }
}

// ------ finalize: stats -> scale/shift; fold next layer's W1' and c ------
__global__ __launch_bounds__(256) void finalize_kernel(
    const float* __restrict__ partial,
    const float* __restrict__ gamma, const float* __restrict__ beta,
    float* __restrict__ ss, const float* W1next,
    float* __restrict__ W1p, float* __restrict__ cvec)
{
    __shared__ float red[256];
    __shared__ float sscl[DIM], sshl[DIM];
    int t = threadIdx.x;
    int c = t & 63;
    int chunk = t >> 6;
    float a = 0.f;
    for (int p = chunk; p < NSLOTS2; p += 4) a += partial[(long)p * 64 + c];
    red[t] = a; __syncthreads();
    if (t < 64) red[t] = red[t] + red[t + 64] + red[t + 128] + red[t + 192];
    __syncthreads();
    if (t < DIM) {
        const float invN = 1.0f / (float)N_NODES;
        float S = red[t], Q = red[t + DIM];
        float mu = S * invN;
        float var = Q * invN - mu * mu;
        float scale = gamma[t] * rsqrtf(var + BN_EPS);
        float shift = beta[t] - mu * scale;
        ss[t] = scale; ss[DIM + t] = shift;
        sscl[t] = scale; sshl[t] = shift;
    }
    __syncthreads();
    if (W1next) {
        for (int i = t; i < DIM * DIM; i += 256)
            W1p[i] = sscl[i >> 5] * W1next[i];
        if (t < DIM) {
            float cv = 0.f;
            for (int k = 0; k < DIM; ++k)
                cv += sshl[k] * W1next[k * DIM + t];
            cvec[t] = cv;
        }
    }
}

// ------- pool: pooled[g] += affine(zfp16[node]); sorted-batch LDS dedup -------
__global__ __launch_bounds__(256) void pool_kernel(
    const unsigned short* __restrict__ z, const int* __restrict__ batch,
    const float* __restrict__ ss, float* __restrict__ pooled)
{
    __shared__ float acc[32][32];
    __shared__ int slot[32];
    __shared__ int segg[32];
    __shared__ int nsegS;
    __shared__ float scl[DIM], shl[DIM];
    int tid = threadIdx.x;
    for (int i = tid; i < 1024; i += 256) ((float*)acc)[i] = 0.f;
    if (tid < DIM) { scl[tid] = ss[tid]; shl[tid] = ss[DIM + tid]; }
    int nodeBase = blockIdx.x * 32;
    if (tid < 32) {
        int nd = nodeBase + tid;
        int gv = batch[nd];
        int flag = (tid == 0) ? 1 : (gv != batch[nd - 1]);
        unsigned long long m = __ballot(flag);
        int s = __popcll(m & ((2ull << tid) - 1ull)) - 1;
        slot[tid] = s;
        if (flag) segg[s] = gv;
        if (tid == 0) nsegS = __popcll(m);
    }
    __syncthreads();

    int ln = tid >> 3;
    int p = tid & 7;
    long node = nodeBase + ln;
    uint2 u = ((const uint2*)z)[node * 8 + p];
    int c = p * 4;
    float2 f01 = up2(u.x), f23 = up2(u.y);
    float vx = fmaf(f01.x, scl[c+0], shl[c+0]);
    float vy = fmaf(f01.y, scl[c+1], shl[c+1]);
    float vz = fmaf(f23.x, scl[c+2], shl[c+2]);
    float vw = fmaf(f23.y, scl[c+3], shl[c+3]);
    int s = slot[ln];
    atomicAdd(&acc[s][c+0], vx);
    atomicAdd(&acc[s][c+1], vy);
    atomicAdd(&acc[s][c+2], vz);
    atomicAdd(&acc[s][c+3], vw);
    __syncthreads();

    int total = nsegS * 32;
    for (int i = tid; i < total; i += 256) {
        int r = i >> 5, dd = i & 31;
        float val = acc[r][dd];
        if (val != 0.f) atomicAdd(&pooled[(long)segg[r] * DIM + dd], val);
    }
}

// ---------------- final FC + ReLU ----------------
__global__ __launch_bounds__(256) void fc_kernel(
    const float* __restrict__ pooled, const float* __restrict__ Wfc,
    const float* __restrict__ bfc, float* __restrict__ out)
{
    __shared__ float Wl[DIM * OUTD];   // 16 KB
    for (int i = threadIdx.x; i < DIM * OUTD; i += 256) Wl[i] = Wfc[i];
    __syncthreads();
    int t = blockIdx.x * 256 + threadIdx.x;
    if (t >= N_GRAPHS * OUTD) return;
    int g = t >> 7;
    int o = t & (OUTD - 1);
    float acc = bfc[o];
    const float* pr = pooled + (long)g * DIM;
#pragma unroll
    for (int k = 0; k < DIM; ++k) acc += pr[k] * Wl[k * OUTD + o];
    out[t] = fmaxf(acc, 0.f);
}

extern "C" void kernel_launch(void* const* d_in, const int* in_sizes, int n_in,
                              void* d_out, int out_size, void* d_ws, size_t ws_size,
                              hipStream_t stream) {
    const float* x      = (const float*)d_in[0];
    const int*   ei     = (const int*)  d_in[1];
    const int*   batch  = (const int*)  d_in[2];
    const float* W1_0   = (const float*)d_in[3];
    const float* W1_rest= (const float*)d_in[4];
    const float* b1     = (const float*)d_in[5];
    const float* W2     = (const float*)d_in[6];
    const float* b2     = (const float*)d_in[7];
    const float* gamma  = (const float*)d_in[8];
    const float* beta   = (const float*)d_in[9];
    const float* Wfc    = (const float*)d_in[10];
    const float* bfc    = (const float*)d_in[11];
    float* out = (float*)d_out;

    int* wsi = (int*)d_ws;
    const size_t nf = (size_t)N_NODES * DIM;                   // 3.2M elems
    const size_t BD = (size_t)NBUK * STRIDE;                   // 1,801,728 ints
    // bdata (7.2 MB) overlays zfpA (6.4 MB): gemm1 runs after cfill2
    int*   bdata  = wsi;
    unsigned short* zfpA = (unsigned short*)wsi;
    unsigned short* zfpB = (unsigned short*)(wsi + BD);
    int*   edge_src = wsi + BD + nf / 2;                       // 1.6M ints
    int*   offs   = edge_src + N_EDGES;                        // 100,001
    int*   bcnt   = offs + (N_NODES + 1);                      // 391
    int*   bbase  = bcnt + NBUK;                               // 392
    float* pooled = (float*)(bbase + NBUK + 1);                // 65,536
    float* partial= pooled + (size_t)N_GRAPHS * DIM;           // 5*49*64
    float* ss     = partial + (size_t)NLAYERS * NSLOTS2 * 2 * DIM;
    float* W1p    = ss + NLAYERS * 2 * DIM;
    float* cvec   = W1p + NLAYERS * DIM * DIM;

    hipMemsetAsync(pooled, 0,
        ((size_t)N_GRAPHS * DIM + (size_t)NLAYERS * NSLOTS2 * 2 * DIM) *
        sizeof(float), stream);
    hipMemsetAsync(bcnt, 0, (size_t)NBUK * sizeof(int), stream);

    const int grpBlocks = (N_NODES * 8) / 256;                 // 3125
    const int NBLK = (N_EDGES + EPB - 1) / EPB;                // 391

    // CSR build: block-aggregated bucket fill -> scan -> per-bucket sort
    bfill2_kernel<<<NBLK, 256, 0, stream>>>(ei, bcnt, bdata);
    bscan_kernel<<<1, 512, 0, stream>>>(bcnt, bbase);
    cfill2_kernel<<<NBUK, 256, 0, stream>>>(bcnt, bbase, bdata, edge_src, offs);

    // layer 0 input projection -> fp16 (overlays bdata; after cfill2)
    gemm1_kernel<<<grpBlocks, 256, 0, stream>>>(x, W1_0, zfpA);

    // layer 0: gather y0, no matmul fold
    layer_kernel<false><<<N_NODES / NPB, 256, 0, stream>>>(
        offs, edge_src, zfpA, nullptr, nullptr,
        b1, W2, b2, zfpB, partial);
    finalize_kernel<<<1, 256, 0, stream>>>(
        partial, gamma, beta, ss,
        W1_rest, W1p + DIM * DIM, cvec + DIM);

    // layers 1..4: fused affine+W1 fold
    const unsigned short* zi = zfpB;
    unsigned short* zo = zfpA;
    for (int i = 1; i < NLAYERS; ++i) {
        layer_kernel<true><<<N_NODES / NPB, 256, 0, stream>>>(
            offs, edge_src, zi,
            W1p + (size_t)i * DIM * DIM, cvec + (size_t)i * DIM,
            b1 + i * DIM, W2 + (size_t)i * DIM * DIM, b2 + i * DIM,
            zo, partial + (size_t)i * NSLOTS2 * 2 * DIM);
        const float* W1next = (i + 1 < NLAYERS) ? (W1_rest + (size_t)i * DIM * DIM)
                                                : nullptr;
        finalize_kernel<<<1, 256, 0, stream>>>(
            partial + (size_t)i * NSLOTS2 * 2 * DIM,
            gamma + i * DIM, beta + i * DIM, ss + i * 2 * DIM,
            W1next, W1p + (size_t)(i + 1) * DIM * DIM,
            cvec + (size_t)(i + 1) * DIM);
        const unsigned short* tmp = zi; zi = zo; zo = (unsigned short*)tmp;
    }

    // zi points at the final layer's output
    pool_kernel<<<N_NODES / 32, 256, 0, stream>>>(
        zi, batch, ss + (NLAYERS - 1) * 2 * DIM, pooled);
    fc_kernel<<<(N_GRAPHS * OUTD) / 256, 256, 0, stream>>>(pooled, Wfc, bfc, out);
}